// Round 14
// baseline (4216.634 us; speedup 1.0000x reference)
//
#include <hip/hip_runtime.h>

#define SEQ   512
#define BATCH 128
#define NFEAT 64
#define HID   256
#define HB    (BATCH * HID)   // 32768
#define NGRP  8               // batch groups (16 batches each)
#define GBLK  32              // blocks per group: 2 layers x 16 col-tiles

// ---------------------------------------------------------------------------
// Persistent 2-layer LSTM, 256 blocks x 256 threads (1 block/CU).
// Group g (32 blocks = 2 layers x 16 col-tiles) owns batches [g*16,g*16+16).
// NEW this round: NO cross-wave K-reduction. Each wave owns one M-tile =
// 4 cols x 4 gates (16 rows) x FULL K (16 k-tiles; layer 0 skips the 6
// all-zero tiles at k>=320). The MFMA accumulator IS the final preact:
// no red buffer, no reduce barrier, no idle half-block. The (gate,col) ->
// (col,gate) redistribution is an in-register 4x4 lane-group transpose
// (2 butterfly stages, 4 __shfl_xor). All 256 threads then do one
// gate-set + c-update + tagged store. 3 independent accumulators
// (hi*hi, hi*lo, lo*hi) keep dependent-MFMA chains <= 16 deep.
// Exchange: r12-verified single-trip tagged words -- u32 [bf16_hi:16 |
// bf16_lo&FFFC:14 | tag:2], tag=((t>>2)%3)+1, 4 slots (t&3), staged-progress
// flags for back-pressure (own >= t-2; cross L0->L1 >= t-3), bounded spins.
// Memory primitives: ONLY agent-scope relaxed atomics (r6/r9/r10/r12).
// sc0-only exchange blacklisted (r8 timeout, r11 wrong data).
// ---------------------------------------------------------------------------

typedef unsigned u32;
typedef unsigned long long u64;
typedef __attribute__((ext_vector_type(8))) short  short8;
typedef __attribute__((ext_vector_type(4))) float  f32x4;
typedef __attribute__((ext_vector_type(4))) unsigned short us4;

__device__ __forceinline__ unsigned short f2bf(float f) {  // RNE
    union { float f; unsigned u; } c; c.f = f;
    unsigned r = c.u + 0x7FFF + ((c.u >> 16) & 1);
    return (unsigned short)(r >> 16);
}
__device__ __forceinline__ float bf2f(unsigned short h) {
    union { float f; unsigned u; } c; c.u = ((unsigned)h) << 16;
    return c.f;
}

// agent-scope relaxed atomics -- the ONLY cross-block memory primitives.
__device__ __forceinline__ u64 ald64(const u64* p) {
    return __hip_atomic_load(p, __ATOMIC_RELAXED, __HIP_MEMORY_SCOPE_AGENT);
}
__device__ __forceinline__ u32 ald32(const u32* p) {
    return __hip_atomic_load(p, __ATOMIC_RELAXED, __HIP_MEMORY_SCOPE_AGENT);
}
__device__ __forceinline__ void ast32(u32* p, u32 v) {
    __hip_atomic_store(p, v, __ATOMIC_RELAXED, __HIP_MEMORY_SCOPE_AGENT);
}
__device__ __forceinline__ void agld16(const u32* p, u32 w[16]) {
    const u64* q = (const u64*)p;
    #pragma unroll
    for (int i = 0; i < 8; ++i) {
        const u64 v = ald64(q + i);
        w[2 * i] = (u32)v; w[2 * i + 1] = (u32)(v >> 32);
    }
}
__device__ __forceinline__ void spin16(const u32* p, u32 w[16], u32 tag) {
    int guard = 0;
    agld16(p, w);
    for (;;) {
        bool ok = true;
        #pragma unroll
        for (int i = 0; i < 16; ++i) ok &= ((w[i] & 3u) == tag);
        if (ok || ++guard >= (1 << 14)) break;
        agld16(p, w);
    }
}

__global__ __launch_bounds__(256, 1) void lstm_persist(
    const float* __restrict__ X,      // [512][128][64]
    const float* __restrict__ w_ih0,  // [1024][64]
    const float* __restrict__ w_hh0,  // [1024][256]
    const float* __restrict__ b_ih0,
    const float* __restrict__ b_hh0,
    const float* __restrict__ w_ih1,  // [1024][256]
    const float* __restrict__ w_hh1,  // [1024][256]
    const float* __restrict__ b_ih1,
    const float* __restrict__ b_hh1,
    u32* __restrict__ h0p,            // [4 slots][HB] tagged packed words
    u32* __restrict__ h1p,            // [4 slots][HB] tagged packed words
    u32* __restrict__ flags)          // [NGRP][GBLK] stride 32 u32
{
    const int bid = blockIdx.x;
    const int tid = threadIdx.x;
    const int g     = bid >> 5;        // batch group 0..7
    const int rk    = bid & 31;        // rank in group
    const int layer = rk >> 4;         // 0 or 1
    const int ct    = rk & 15;         // col tile
    const int b0    = g * 16;          // 16 batches
    const int j0    = ct * 16;         // 16 h-cols

    const int wave = tid >> 6;         // owns cols j0 + wave*4 .. +3 (all gates)
    const int l    = tid & 63;
    const int kq   = l >> 4;           // k-quarter within a k-tile
    const int ar   = l & 15;           // A row (gate*4+coff) / B col (batch)

    __shared__ __align__(16) unsigned short hsh[16 * 512];
    __shared__ __align__(16) unsigned short hsl[16 * 512];
    __shared__ float bbuf[4][16];      // bias sums [gate][col]

    // zero planes once (layer0's k >= 320 must stay 0 forever)
    {
        const short8 z8 = {0, 0, 0, 0, 0, 0, 0, 0};
        for (int i = tid; i < 16 * 512 / 8; i += 256) {
            ((short8*)hsh)[i] = z8;
            ((short8*)hsl)[i] = z8;
        }
    }
    if (tid < 64) {
        const int gg = tid >> 4, cc = tid & 15;
        const float* bi_ = layer ? b_ih1 : b_ih0;
        const float* bh_ = layer ? b_hh1 : b_hh0;
        bbuf[gg][cc] = bi_[gg * 256 + j0 + cc] + bh_[gg * 256 + j0 + cc];
    }

    // ---- A-fragments: wave's M-tile rows = gate*4 + coff, full K ----
    // Frag layout (16x16x32): lane l holds A[row=l&15][k=(l>>4)*8 + j], j=0..7.
    short8 Ahi[16], Alo[16];          // [ktile]
    {
        const short8 z8 = {0, 0, 0, 0, 0, 0, 0, 0};
        const int gate = ar >> 2, coff = ar & 3;
        const int row  = gate * 256 + j0 + wave * 4 + coff;
        #pragma unroll
        for (int KT = 0; KT < 16; ++KT) {
            const int k = KT * 32 + kq * 8;   // concat-k floats
            const float* src = nullptr;
            if (layer) {
                src = (k < 256) ? (w_ih1 + (size_t)row * 256 + k)
                                : (w_hh1 + (size_t)row * 256 + (k - 256));
            } else {
                if (k < 64)       src = w_ih0 + (size_t)row * 64 + k;
                else if (k < 320) src = w_hh0 + (size_t)row * 256 + (k - 64);
            }
            short8 hi8 = z8, lo8 = z8;
            if (src) {
                const float4 a = ((const float4*)src)[0];
                const float4 bq = ((const float4*)src)[1];
                const float wv[8] = {a.x, a.y, a.z, a.w, bq.x, bq.y, bq.z, bq.w};
                #pragma unroll
                for (int i = 0; i < 8; ++i) {
                    const unsigned short h = f2bf(wv[i]);
                    hi8[i] = (short)h;
                    lo8[i] = (short)f2bf(wv[i] - bf2f(h));
                }
            }
            Ahi[KT] = hi8;
            Alo[KT] = lo8;
        }
    }
    const int KTMAX = layer ? 16 : 10;   // L0: k >= 320 tiles are all-zero

    // output ownership after transpose: (batch = l&15, col = wave*4 + (l>>4))
    const int oq = l >> 4, ob = l & 15;
    float creg = 0.f;

    u32* hown  = layer ? h1p : h0p;
    u32* gflag = flags + (size_t)g * GBLK * 32;
    const int hoff = layer ? 256 : 64;

    // X prefetch (layer 0)
    const int pb = tid >> 4, pf = tid & 15;
    float4 xpf = make_float4(0.f, 0.f, 0.f, 0.f);
    if (!layer)
        xpf = ((const float4*)(X + (size_t)(b0 + pb) * NFEAT))[pf];

    __syncthreads();  // LDS zero + bias visible

    for (int t = 0; t < SEQ; ++t) {
        const int sp  = (t - 1) & 3;
        const int st  = t & 3;
        const u32 tgp = (t > 0) ? ((u32)((t - 1) >> 2) % 3u) + 1u : 0u;
        const u32 tgc = ((u32)(t >> 2) % 3u) + 1u;

        // back-pressure first check (non-blocking; verified after staging)
        const u32* faddr = nullptr; u32 fthr = 0, fval = 0;
        if (tid < 16) {
            if (tid != ct && t >= 3) {
                faddr = &gflag[(layer * 16 + tid) * 32];
                fthr  = (u32)(t - 2);
            }
        } else if (tid < 32 && layer == 0 && t >= 4) {
            faddr = &gflag[(16 + (tid - 16)) * 32];
            fthr  = (u32)(t - 3);
        }
        if (faddr) fval = ald32(faddr);

        const int b = tid >> 4, f0 = tid & 15;   // staging roles
        const int swz = (b & 7) << 3;

        if (t > 0) {  // h_prev (own layer): spin on tagged words
            const u32* hp = hown + (size_t)sp * HB + (size_t)(b0 + b) * HID + f0 * 16;
            u32 w[16];
            spin16(hp, w, tgp);
            short8 h0v, l0v, h1v, l1v;
            #pragma unroll
            for (int i = 0; i < 8; ++i) {
                h0v[i] = (short)(w[i] >> 16);     l0v[i] = (short)(w[i] & 0xFFFCu);
                h1v[i] = (short)(w[8 + i] >> 16); l1v[i] = (short)(w[8 + i] & 0xFFFCu);
            }
            const int us = b * 512 + hoff + f0 * 16;
            *(short8*)&hsh[us ^ swz]       = h0v;
            *(short8*)&hsh[(us + 8) ^ swz] = h1v;
            *(short8*)&hsl[us ^ swz]       = l0v;
            *(short8*)&hsl[(us + 8) ^ swz] = l1v;
        }
        if (layer) {  // x = h0[t]: spin on tagged words
            const u32* xp = h0p + (size_t)st * HB + (size_t)(b0 + b) * HID + f0 * 16;
            u32 w[16];
            spin16(xp, w, tgc);
            short8 h0v, l0v, h1v, l1v;
            #pragma unroll
            for (int i = 0; i < 8; ++i) {
                h0v[i] = (short)(w[i] >> 16);     l0v[i] = (short)(w[i] & 0xFFFCu);
                h1v[i] = (short)(w[8 + i] >> 16); l1v[i] = (short)(w[8 + i] & 0xFFFCu);
            }
            const int us = b * 512 + f0 * 16;
            *(short8*)&hsh[us ^ swz]       = h0v;
            *(short8*)&hsh[(us + 8) ^ swz] = h1v;
            *(short8*)&hsl[us ^ swz]       = l0v;
            *(short8*)&hsl[(us + 8) ^ swz] = l1v;
        } else {      // x from prefetched X (convert fp32 -> hi/lo)
            const float xv[4] = {xpf.x, xpf.y, xpf.z, xpf.w};
            us4 xh, xl;
            #pragma unroll
            for (int i = 0; i < 4; ++i) {
                const unsigned short hh = f2bf(xv[i]);
                xh[i] = hh;
                xl[i] = (unsigned short)(f2bf(xv[i] - bf2f(hh)) & 0xFFFF);
            }
            const int us = pb * 512 + pf * 4;
            const int sw = (pb & 7) << 3;
            *(us4*)&hsh[us ^ sw] = xh;
            *(us4*)&hsl[us ^ sw] = xl;
        }

        if (faddr) {   // back-pressure verify (stale thresholds; rarely spins)
            int guard = 0;
            while (fval < fthr && ++guard < (1 << 16)) fval = ald32(faddr);
        }
        __syncthreads();  // S1: staged planes visible

        if (tid == 0)
            ast32(&gflag[rk * 32], (u32)(t + 1));   // staged-progress flag

        if (!layer && t + 1 < SEQ)
            xpf = ((const float4*)(X + (size_t)(t + 1) * BATCH * NFEAT
                                     + (size_t)(b0 + pb) * NFEAT))[pf];

        // ---- MFMA: full-K M-tile, 3 independent accumulator chains ----
        f32x4 aHH = (f32x4){0.f, 0.f, 0.f, 0.f};
        f32x4 aHL = (f32x4){0.f, 0.f, 0.f, 0.f};
        f32x4 aLH = (f32x4){0.f, 0.f, 0.f, 0.f};
        for (int KT = 0; KT < KTMAX; ++KT) {
            const int us = ar * 512 + KT * 32 + kq * 8;
            const int uswz = us ^ ((ar & 7) << 3);
            const short8 bh = *(const short8*)&hsh[uswz];
            const short8 bl = *(const short8*)&hsl[uswz];
            aHH = __builtin_amdgcn_mfma_f32_16x16x32_bf16(Ahi[KT], bh, aHH, 0, 0, 0);
            aHL = __builtin_amdgcn_mfma_f32_16x16x32_bf16(Ahi[KT], bl, aHL, 0, 0, 0);
            aLH = __builtin_amdgcn_mfma_f32_16x16x32_bf16(Alo[KT], bh, aLH, 0, 0, 0);
        }
        // preacts: source layout (reg c, lane-group g) = (coff c, gate g), b = l&15
        float v0 = aHH[0] + aHL[0] + aLH[0];
        float v1 = aHH[1] + aHL[1] + aLH[1];
        float v2 = aHH[2] + aHL[2] + aLH[2];
        float v3 = aHH[3] + aHL[3] + aLH[3];

        // ---- in-register 4x4 transpose: (coff,gate) -> (gate,coff) ----
        {   // stage 1: swap reg bit0 <-> lane bit4
            const bool hi = (l >> 4) & 1;
            float s0 = hi ? v0 : v1;
            float s1 = hi ? v2 : v3;
            const float r0 = __shfl_xor(s0, 16);
            const float r1 = __shfl_xor(s1, 16);
            if (hi) { v0 = r0; v2 = r1; } else { v1 = r0; v3 = r1; }
        }
        {   // stage 2: swap reg bit1 <-> lane bit5
            const bool hi = (l >> 5) & 1;
            float s0 = hi ? v0 : v2;
            float s1 = hi ? v1 : v3;
            const float r0 = __shfl_xor(s0, 32);
            const float r1 = __shfl_xor(s1, 32);
            if (hi) { v0 = r0; v1 = r1; } else { v2 = r0; v3 = r1; }
        }
        // now v0..v3 = gates i,f,g,o for (batch ob, col j0 + wave*4 + oq)

        {
            const int colq = wave * 4 + oq;
            const float pi  = v0 + bbuf[0][colq];
            const float pf_ = v1 + bbuf[1][colq];
            const float pg  = v2 + bbuf[2][colq];
            const float po  = v3 + bbuf[3][colq];
            const float ig  = 1.0f / (1.0f + __expf(-pi));
            const float fg  = 1.0f / (1.0f + __expf(-pf_));
            const float gg_ = tanhf(pg);
            const float og  = 1.0f / (1.0f + __expf(-po));
            creg = fg * creg + ig * gg_;
            const float hv = og * tanhf(creg);
            const unsigned short hi = f2bf(hv);
            const unsigned short lo = f2bf(hv - bf2f(hi));
            ast32(&hown[(size_t)st * HB + (size_t)(b0 + ob) * HID + j0 + colq],
                  ((u32)hi << 16) | ((u32)lo & 0xFFFCu) | tgc);
        }
        __syncthreads();  // S2: all B-frag LDS reads done before next staging
    }
}

// out[b] = dot(h1_last[b,:], fc_w) + fc_b ; h1[511] lives in slot 511&3 = 3
__global__ __launch_bounds__(64) void fc_kernel(
    const u32* __restrict__ h1last_p,
    const float* __restrict__ fc_w,
    const float* __restrict__ fc_b,
    float* __restrict__ out)
{
    const int b    = blockIdx.x;
    const int lane = threadIdx.x;
    float sum = 0.0f;
    #pragma unroll
    for (int k = lane; k < HID; k += 64) {
        const u32 w = h1last_p[(size_t)b * HID + k];
        const float h = bf2f((unsigned short)(w >> 16))
                      + bf2f((unsigned short)(w & 0xFFFCu));
        sum += h * fc_w[k];
    }
    #pragma unroll
    for (int off = 32; off > 0; off >>= 1)
        sum += __shfl_down(sum, off);
    if (lane == 0) out[b] = sum + fc_b[0];
}

extern "C" void kernel_launch(void* const* d_in, const int* in_sizes, int n_in,
                              void* d_out, int out_size, void* d_ws, size_t ws_size,
                              hipStream_t stream)
{
    const float* X     = (const float*)d_in[0];
    const float* w_ih0 = (const float*)d_in[1];
    const float* w_hh0 = (const float*)d_in[2];
    const float* b_ih0 = (const float*)d_in[3];
    const float* b_hh0 = (const float*)d_in[4];
    const float* w_ih1 = (const float*)d_in[5];
    const float* w_hh1 = (const float*)d_in[6];
    const float* b_ih1 = (const float*)d_in[7];
    const float* b_hh1 = (const float*)d_in[8];
    const float* fc_w  = (const float*)d_in[9];
    const float* fc_b  = (const float*)d_in[10];

    u32* h0p   = (u32*)d_ws;             // [4][HB] tagged packed
    u32* h1p   = h0p + 4 * HB;           // [4][HB] tagged packed
    u32* flags = h1p + 4 * HB;           // NGRP*GBLK slots, stride 32 u32

    // zero h slots (tag=0) + flags every call; graph replays this memset so
    // stale tags/flags never leak across replays
    const size_t zbytes = (size_t)(8 * HB + NGRP * GBLK * 32) * sizeof(u32);
    (void)hipMemsetAsync(d_ws, 0, zbytes, stream);

    lstm_persist<<<NGRP * GBLK, 256, 0, stream>>>(X,
        w_ih0, w_hh0, b_ih0, b_hh0,
        w_ih1, w_hh1, b_ih1, b_hh1,
        h0p, h1p, flags);

    // h1 for t=511 lives in slot (511 & 3) = 3
    fc_kernel<<<BATCH, 64, 0, stream>>>(h1p + 3 * HB, fc_w, fc_b, (float*)d_out);
}

// Round 15
// 2633.966 us; speedup vs baseline: 1.6009x; 1.6009x over previous
//
#include <hip/hip_runtime.h>

#define SEQ   512
#define BATCH 128
#define NFEAT 64
#define HID   256
#define HB    (BATCH * HID)   // 32768
#define NGRP  8               // batch groups (16 batches each)
#define GBLK  32              // blocks per group: 2 layers x 16 col-tiles

// ---------------------------------------------------------------------------
// Persistent 2-layer LSTM, 256 blocks x 256 threads (1 block/CU).
// Group g (32 blocks = 2 layers x 16 col-tiles) owns batches [g*16,g*16+16).
// Per-wave FULL-K M-tile (r14 design, r14-verified numerics): each wave owns
// 4 cols x 4 gates (16 rows) x full K; the MFMA accumulator IS the final
// preact (no cross-wave reduction, no red buffer, no reduce barrier). The
// (gate,col)->(col,gate) redistribution is an in-register 4x4 lane-group
// transpose (2 butterfly stages). 3 independent accumulators (hi*hi, hi*lo,
// lo*hi). FIX this round (r14 post-mortem): the MFMA K-loop bound was
// RUNTIME (layer ? 16 : 10) -> no full unroll -> Ahi[KT]/Alo[KT] runtime-
// indexed -> compiler demoted both arrays to SCRATCH (VGPR=52, +1.3GB fetch).
// Now: branch on block-uniform `layer` into two #pragma unroll loops with
// LITERAL trip counts so every fragment index is compile-time and the
// weights stay register-resident (rule #20).
// Exchange: r12-verified single-trip tagged words -- u32 [bf16_hi:16 |
// bf16_lo&FFFC:14 | tag:2], tag=((t>>2)%3)+1, 4 slots (t&3), staged-progress
// flags for back-pressure (own >= t-2; cross L0->L1 >= t-3), bounded spins.
// Memory primitives: ONLY agent-scope relaxed atomics (r6/r9/r10/r12).
// sc0-only exchange blacklisted (r8 timeout, r11 wrong data).
// ---------------------------------------------------------------------------

typedef unsigned u32;
typedef unsigned long long u64;
typedef __attribute__((ext_vector_type(8))) short  short8;
typedef __attribute__((ext_vector_type(4))) float  f32x4;
typedef __attribute__((ext_vector_type(4))) unsigned short us4;

__device__ __forceinline__ unsigned short f2bf(float f) {  // RNE
    union { float f; unsigned u; } c; c.f = f;
    unsigned r = c.u + 0x7FFF + ((c.u >> 16) & 1);
    return (unsigned short)(r >> 16);
}
__device__ __forceinline__ float bf2f(unsigned short h) {
    union { float f; unsigned u; } c; c.u = ((unsigned)h) << 16;
    return c.f;
}

// agent-scope relaxed atomics -- the ONLY cross-block memory primitives.
__device__ __forceinline__ u64 ald64(const u64* p) {
    return __hip_atomic_load(p, __ATOMIC_RELAXED, __HIP_MEMORY_SCOPE_AGENT);
}
__device__ __forceinline__ u32 ald32(const u32* p) {
    return __hip_atomic_load(p, __ATOMIC_RELAXED, __HIP_MEMORY_SCOPE_AGENT);
}
__device__ __forceinline__ void ast32(u32* p, u32 v) {
    __hip_atomic_store(p, v, __ATOMIC_RELAXED, __HIP_MEMORY_SCOPE_AGENT);
}
__device__ __forceinline__ void agld16(const u32* p, u32 w[16]) {
    const u64* q = (const u64*)p;
    #pragma unroll
    for (int i = 0; i < 8; ++i) {
        const u64 v = ald64(q + i);
        w[2 * i] = (u32)v; w[2 * i + 1] = (u32)(v >> 32);
    }
}
__device__ __forceinline__ void spin16(const u32* p, u32 w[16], u32 tag) {
    int guard = 0;
    agld16(p, w);
    for (;;) {
        bool ok = true;
        #pragma unroll
        for (int i = 0; i < 16; ++i) ok &= ((w[i] & 3u) == tag);
        if (ok || ++guard >= (1 << 14)) break;
        agld16(p, w);
    }
}

__global__ __launch_bounds__(256, 1) void lstm_persist(
    const float* __restrict__ X,      // [512][128][64]
    const float* __restrict__ w_ih0,  // [1024][64]
    const float* __restrict__ w_hh0,  // [1024][256]
    const float* __restrict__ b_ih0,
    const float* __restrict__ b_hh0,
    const float* __restrict__ w_ih1,  // [1024][256]
    const float* __restrict__ w_hh1,  // [1024][256]
    const float* __restrict__ b_ih1,
    const float* __restrict__ b_hh1,
    u32* __restrict__ h0p,            // [4 slots][HB] tagged packed words
    u32* __restrict__ h1p,            // [4 slots][HB] tagged packed words
    u32* __restrict__ flags)          // [NGRP][GBLK] stride 32 u32
{
    const int bid = blockIdx.x;
    const int tid = threadIdx.x;
    const int g     = bid >> 5;        // batch group 0..7
    const int rk    = bid & 31;        // rank in group
    const int layer = rk >> 4;         // 0 or 1
    const int ct    = rk & 15;         // col tile
    const int b0    = g * 16;          // 16 batches
    const int j0    = ct * 16;         // 16 h-cols

    const int wave = tid >> 6;         // owns cols j0 + wave*4 .. +3 (all gates)
    const int l    = tid & 63;
    const int kq   = l >> 4;           // k-quarter within a k-tile
    const int ar   = l & 15;           // A row (gate*4+coff) / B col (batch)

    __shared__ __align__(16) unsigned short hsh[16 * 512];
    __shared__ __align__(16) unsigned short hsl[16 * 512];
    __shared__ float bbuf[4][16];      // bias sums [gate][col]

    // zero planes once (layer0's k >= 320 must stay 0 forever)
    {
        const short8 z8 = {0, 0, 0, 0, 0, 0, 0, 0};
        for (int i = tid; i < 16 * 512 / 8; i += 256) {
            ((short8*)hsh)[i] = z8;
            ((short8*)hsl)[i] = z8;
        }
    }
    if (tid < 64) {
        const int gg = tid >> 4, cc = tid & 15;
        const float* bi_ = layer ? b_ih1 : b_ih0;
        const float* bh_ = layer ? b_hh1 : b_hh0;
        bbuf[gg][cc] = bi_[gg * 256 + j0 + cc] + bh_[gg * 256 + j0 + cc];
    }

    // ---- A-fragments: wave's M-tile rows = gate*4 + coff, full K ----
    // Frag layout (16x16x32): lane l holds A[row=l&15][k=(l>>4)*8 + j], j=0..7.
    // Statically indexed everywhere (init below + unrolled compute loops) so
    // they stay in VGPRs (128 regs).
    short8 Ahi[16], Alo[16];          // [ktile]
    {
        const short8 z8 = {0, 0, 0, 0, 0, 0, 0, 0};
        const int gate = ar >> 2, coff = ar & 3;
        const int row  = gate * 256 + j0 + wave * 4 + coff;
        #pragma unroll
        for (int KT = 0; KT < 16; ++KT) {
            const int k = KT * 32 + kq * 8;   // concat-k floats
            const float* src = nullptr;
            if (layer) {
                src = (k < 256) ? (w_ih1 + (size_t)row * 256 + k)
                                : (w_hh1 + (size_t)row * 256 + (k - 256));
            } else {
                if (k < 64)       src = w_ih0 + (size_t)row * 64 + k;
                else if (k < 320) src = w_hh0 + (size_t)row * 256 + (k - 64);
            }
            short8 hi8 = z8, lo8 = z8;
            if (src) {
                const float4 a = ((const float4*)src)[0];
                const float4 bq = ((const float4*)src)[1];
                const float wv[8] = {a.x, a.y, a.z, a.w, bq.x, bq.y, bq.z, bq.w};
                #pragma unroll
                for (int i = 0; i < 8; ++i) {
                    const unsigned short h = f2bf(wv[i]);
                    hi8[i] = (short)h;
                    lo8[i] = (short)f2bf(wv[i] - bf2f(h));
                }
            }
            Ahi[KT] = hi8;
            Alo[KT] = lo8;
        }
    }

    // output ownership after transpose: (batch = l&15, col = wave*4 + (l>>4))
    const int oq = l >> 4, ob = l & 15;
    float creg = 0.f;

    u32* hown  = layer ? h1p : h0p;
    u32* gflag = flags + (size_t)g * GBLK * 32;
    const int hoff = layer ? 256 : 64;

    // X prefetch (layer 0)
    const int pb = tid >> 4, pf = tid & 15;
    float4 xpf = make_float4(0.f, 0.f, 0.f, 0.f);
    if (!layer)
        xpf = ((const float4*)(X + (size_t)(b0 + pb) * NFEAT))[pf];

    __syncthreads();  // LDS zero + bias visible

    for (int t = 0; t < SEQ; ++t) {
        const int sp  = (t - 1) & 3;
        const int st  = t & 3;
        const u32 tgp = (t > 0) ? ((u32)((t - 1) >> 2) % 3u) + 1u : 0u;
        const u32 tgc = ((u32)(t >> 2) % 3u) + 1u;

        // back-pressure first check (non-blocking; verified after staging)
        const u32* faddr = nullptr; u32 fthr = 0, fval = 0;
        if (tid < 16) {
            if (tid != ct && t >= 3) {
                faddr = &gflag[(layer * 16 + tid) * 32];
                fthr  = (u32)(t - 2);
            }
        } else if (tid < 32 && layer == 0 && t >= 4) {
            faddr = &gflag[(16 + (tid - 16)) * 32];
            fthr  = (u32)(t - 3);
        }
        if (faddr) fval = ald32(faddr);

        const int b = tid >> 4, f0 = tid & 15;   // staging roles
        const int swz = (b & 7) << 3;

        if (t > 0) {  // h_prev (own layer): spin on tagged words
            const u32* hp = hown + (size_t)sp * HB + (size_t)(b0 + b) * HID + f0 * 16;
            u32 w[16];
            spin16(hp, w, tgp);
            short8 h0v, l0v, h1v, l1v;
            #pragma unroll
            for (int i = 0; i < 8; ++i) {
                h0v[i] = (short)(w[i] >> 16);     l0v[i] = (short)(w[i] & 0xFFFCu);
                h1v[i] = (short)(w[8 + i] >> 16); l1v[i] = (short)(w[8 + i] & 0xFFFCu);
            }
            const int us = b * 512 + hoff + f0 * 16;
            *(short8*)&hsh[us ^ swz]       = h0v;
            *(short8*)&hsh[(us + 8) ^ swz] = h1v;
            *(short8*)&hsl[us ^ swz]       = l0v;
            *(short8*)&hsl[(us + 8) ^ swz] = l1v;
        }
        if (layer) {  // x = h0[t]: spin on tagged words
            const u32* xp = h0p + (size_t)st * HB + (size_t)(b0 + b) * HID + f0 * 16;
            u32 w[16];
            spin16(xp, w, tgc);
            short8 h0v, l0v, h1v, l1v;
            #pragma unroll
            for (int i = 0; i < 8; ++i) {
                h0v[i] = (short)(w[i] >> 16);     l0v[i] = (short)(w[i] & 0xFFFCu);
                h1v[i] = (short)(w[8 + i] >> 16); l1v[i] = (short)(w[8 + i] & 0xFFFCu);
            }
            const int us = b * 512 + f0 * 16;
            *(short8*)&hsh[us ^ swz]       = h0v;
            *(short8*)&hsh[(us + 8) ^ swz] = h1v;
            *(short8*)&hsl[us ^ swz]       = l0v;
            *(short8*)&hsl[(us + 8) ^ swz] = l1v;
        } else {      // x from prefetched X (convert fp32 -> hi/lo)
            const float xv[4] = {xpf.x, xpf.y, xpf.z, xpf.w};
            us4 xh, xl;
            #pragma unroll
            for (int i = 0; i < 4; ++i) {
                const unsigned short hh = f2bf(xv[i]);
                xh[i] = hh;
                xl[i] = (unsigned short)(f2bf(xv[i] - bf2f(hh)) & 0xFFFF);
            }
            const int us = pb * 512 + pf * 4;
            const int sw = (pb & 7) << 3;
            *(us4*)&hsh[us ^ sw] = xh;
            *(us4*)&hsl[us ^ sw] = xl;
        }

        if (faddr) {   // back-pressure verify (stale thresholds; rarely spins)
            int guard = 0;
            while (fval < fthr && ++guard < (1 << 16)) fval = ald32(faddr);
        }
        __syncthreads();  // S1: staged planes visible

        if (tid == 0)
            ast32(&gflag[rk * 32], (u32)(t + 1));   // staged-progress flag

        if (!layer && t + 1 < SEQ)
            xpf = ((const float4*)(X + (size_t)(t + 1) * BATCH * NFEAT
                                     + (size_t)(b0 + pb) * NFEAT))[pf];

        // ---- MFMA: full-K M-tile, 3 independent accumulator chains ----
        // Two fully-unrolled loops with LITERAL bounds (block-uniform branch):
        // every Ahi/Alo index is compile-time -> fragments stay in VGPRs.
        f32x4 aHH = (f32x4){0.f, 0.f, 0.f, 0.f};
        f32x4 aHL = (f32x4){0.f, 0.f, 0.f, 0.f};
        f32x4 aLH = (f32x4){0.f, 0.f, 0.f, 0.f};
        if (layer) {
            #pragma unroll
            for (int KT = 0; KT < 16; ++KT) {
                const int us = ar * 512 + KT * 32 + kq * 8;
                const int uswz = us ^ ((ar & 7) << 3);
                const short8 bh = *(const short8*)&hsh[uswz];
                const short8 bl = *(const short8*)&hsl[uswz];
                aHH = __builtin_amdgcn_mfma_f32_16x16x32_bf16(Ahi[KT], bh, aHH, 0, 0, 0);
                aHL = __builtin_amdgcn_mfma_f32_16x16x32_bf16(Ahi[KT], bl, aHL, 0, 0, 0);
                aLH = __builtin_amdgcn_mfma_f32_16x16x32_bf16(Alo[KT], bh, aLH, 0, 0, 0);
            }
        } else {
            #pragma unroll
            for (int KT = 0; KT < 10; ++KT) {   // k >= 320 tiles are all-zero
                const int us = ar * 512 + KT * 32 + kq * 8;
                const int uswz = us ^ ((ar & 7) << 3);
                const short8 bh = *(const short8*)&hsh[uswz];
                const short8 bl = *(const short8*)&hsl[uswz];
                aHH = __builtin_amdgcn_mfma_f32_16x16x32_bf16(Ahi[KT], bh, aHH, 0, 0, 0);
                aHL = __builtin_amdgcn_mfma_f32_16x16x32_bf16(Ahi[KT], bl, aHL, 0, 0, 0);
                aLH = __builtin_amdgcn_mfma_f32_16x16x32_bf16(Alo[KT], bh, aLH, 0, 0, 0);
            }
        }
        // preacts: source layout (reg c, lane-group g) = (coff c, gate g), b = l&15
        float v0 = aHH[0] + aHL[0] + aLH[0];
        float v1 = aHH[1] + aHL[1] + aLH[1];
        float v2 = aHH[2] + aHL[2] + aLH[2];
        float v3 = aHH[3] + aHL[3] + aLH[3];

        // ---- in-register 4x4 transpose: (coff,gate) -> (gate,coff) ----
        {   // stage 1: swap reg bit0 <-> lane bit4
            const bool hi = (l >> 4) & 1;
            float s0 = hi ? v0 : v1;
            float s1 = hi ? v2 : v3;
            const float r0 = __shfl_xor(s0, 16);
            const float r1 = __shfl_xor(s1, 16);
            if (hi) { v0 = r0; v2 = r1; } else { v1 = r0; v3 = r1; }
        }
        {   // stage 2: swap reg bit1 <-> lane bit5
            const bool hi = (l >> 5) & 1;
            float s0 = hi ? v0 : v2;
            float s1 = hi ? v1 : v3;
            const float r0 = __shfl_xor(s0, 32);
            const float r1 = __shfl_xor(s1, 32);
            if (hi) { v0 = r0; v1 = r1; } else { v2 = r0; v3 = r1; }
        }
        // now v0..v3 = gates i,f,g,o for (batch ob, col j0 + wave*4 + oq)

        {
            const int colq = wave * 4 + oq;
            const float pi  = v0 + bbuf[0][colq];
            const float pf_ = v1 + bbuf[1][colq];
            const float pg  = v2 + bbuf[2][colq];
            const float po  = v3 + bbuf[3][colq];
            const float ig  = 1.0f / (1.0f + __expf(-pi));
            const float fg  = 1.0f / (1.0f + __expf(-pf_));
            const float gg_ = tanhf(pg);
            const float og  = 1.0f / (1.0f + __expf(-po));
            creg = fg * creg + ig * gg_;
            const float hv = og * tanhf(creg);
            const unsigned short hi = f2bf(hv);
            const unsigned short lo = f2bf(hv - bf2f(hi));
            ast32(&hown[(size_t)st * HB + (size_t)(b0 + ob) * HID + j0 + colq],
                  ((u32)hi << 16) | ((u32)lo & 0xFFFCu) | tgc);
        }
        __syncthreads();  // S2: all B-frag LDS reads done before next staging
    }
}

// out[b] = dot(h1_last[b,:], fc_w) + fc_b ; h1[511] lives in slot 511&3 = 3
__global__ __launch_bounds__(64) void fc_kernel(
    const u32* __restrict__ h1last_p,
    const float* __restrict__ fc_w,
    const float* __restrict__ fc_b,
    float* __restrict__ out)
{
    const int b    = blockIdx.x;
    const int lane = threadIdx.x;
    float sum = 0.0f;
    #pragma unroll
    for (int k = lane; k < HID; k += 64) {
        const u32 w = h1last_p[(size_t)b * HID + k];
        const float h = bf2f((unsigned short)(w >> 16))
                      + bf2f((unsigned short)(w & 0xFFFCu));
        sum += h * fc_w[k];
    }
    #pragma unroll
    for (int off = 32; off > 0; off >>= 1)
        sum += __shfl_down(sum, off);
    if (lane == 0) out[b] = sum + fc_b[0];
}

extern "C" void kernel_launch(void* const* d_in, const int* in_sizes, int n_in,
                              void* d_out, int out_size, void* d_ws, size_t ws_size,
                              hipStream_t stream)
{
    const float* X     = (const float*)d_in[0];
    const float* w_ih0 = (const float*)d_in[1];
    const float* w_hh0 = (const float*)d_in[2];
    const float* b_ih0 = (const float*)d_in[3];
    const float* b_hh0 = (const float*)d_in[4];
    const float* w_ih1 = (const float*)d_in[5];
    const float* w_hh1 = (const float*)d_in[6];
    const float* b_ih1 = (const float*)d_in[7];
    const float* b_hh1 = (const float*)d_in[8];
    const float* fc_w  = (const float*)d_in[9];
    const float* fc_b  = (const float*)d_in[10];

    u32* h0p   = (u32*)d_ws;             // [4][HB] tagged packed
    u32* h1p   = h0p + 4 * HB;           // [4][HB] tagged packed
    u32* flags = h1p + 4 * HB;           // NGRP*GBLK slots, stride 32 u32

    // zero h slots (tag=0) + flags every call; graph replays this memset so
    // stale tags/flags never leak across replays
    const size_t zbytes = (size_t)(8 * HB + NGRP * GBLK * 32) * sizeof(u32);
    (void)hipMemsetAsync(d_ws, 0, zbytes, stream);

    lstm_persist<<<NGRP * GBLK, 256, 0, stream>>>(X,
        w_ih0, w_hh0, b_ih0, b_hh0,
        w_ih1, w_hh1, b_ih1, b_hh1,
        h0p, h1p, flags);

    // h1 for t=511 lives in slot (511 & 3) = 3
    fc_kernel<<<BATCH, 64, 0, stream>>>(h1p + 3 * HB, fc_w, fc_b, (float*)d_out);
}

// Round 16
// 2558.375 us; speedup vs baseline: 1.6482x; 1.0295x over previous
//
#include <hip/hip_runtime.h>

#define SEQ   512
#define BATCH 128
#define NFEAT 64
#define HID   256
#define HB    (BATCH * HID)   // 32768
#define NGRP  8               // batch groups (16 batches each)
#define GBLK  32              // blocks per group: 2 layers x 16 col-tiles

// ---------------------------------------------------------------------------
// Persistent 2-layer LSTM, 256 blocks x 256 threads (1 block/CU).
// This is the r10 kernel (best verified: 2096us, absmax 0.0) byte-for-byte,
// with ONE change: the WAIT poll issues 4 independent relaxed loads per spin
// iteration (overlapping in flight) instead of one dependent load per
// iteration -- sampling period ~4x shorter, shaving the observe-latency
// quantization (~0.2-0.4us/step) without touching sync semantics.
// Sync: dependency-shaped flags (r10-verified). Flag[rk]=v <=> block rk
// completed step v-1 (staged, computed, h stored & drained). At step t:
//   L0: own flag0[*]>=t, cross flag1[*]>=t-1;  L1: own flag1[*]>=t,
//   cross flag0[*]>=t+1. One poll phase + one flag post per step.
// h crosses blocks as packed u32 [bf16_hi|bf16_lo] (r9/r10-verified).
// Memory primitives: ONLY agent-scope relaxed atomics (r6/r9/r10-verified).
// sc0-only L2 exchange blacklisted (r8 timeout, r11 wrong data).
// Matmul: r6-verified MFMA bf16 hi/lo split, A-frags resident in VGPRs,
// XOR-swizzled LDS B-planes, partial C as float4 into red[4][4][16][20].
// c state stays in its owning thread's register.
// ---------------------------------------------------------------------------

typedef unsigned u32;
typedef unsigned long long u64;
typedef __attribute__((ext_vector_type(8))) short  short8;
typedef __attribute__((ext_vector_type(4))) float  f32x4;
typedef __attribute__((ext_vector_type(4))) unsigned short us4;

__device__ __forceinline__ unsigned short f2bf(float f) {  // RNE
    union { float f; unsigned u; } c; c.f = f;
    unsigned r = c.u + 0x7FFF + ((c.u >> 16) & 1);
    return (unsigned short)(r >> 16);
}
__device__ __forceinline__ float bf2f(unsigned short h) {
    union { float f; unsigned u; } c; c.u = ((unsigned)h) << 16;
    return c.f;
}

// agent-scope (IF coherence point) relaxed atomics -- the ONLY cross-block
// memory primitives in this kernel (r6/r9/r10-verified codegen).
__device__ __forceinline__ u64 ald64(const u64* p) {
    return __hip_atomic_load(p, __ATOMIC_RELAXED, __HIP_MEMORY_SCOPE_AGENT);
}
__device__ __forceinline__ u32 ald32(const u32* p) {
    return __hip_atomic_load(p, __ATOMIC_RELAXED, __HIP_MEMORY_SCOPE_AGENT);
}
__device__ __forceinline__ void ast32(u32* p, u32 v) {
    __hip_atomic_store(p, v, __ATOMIC_RELAXED, __HIP_MEMORY_SCOPE_AGENT);
}

__global__ __launch_bounds__(256, 1) void lstm_persist(
    const float* __restrict__ X,      // [512][128][64]
    const float* __restrict__ w_ih0,  // [1024][64]
    const float* __restrict__ w_hh0,  // [1024][256]
    const float* __restrict__ b_ih0,
    const float* __restrict__ b_hh0,
    const float* __restrict__ w_ih1,  // [1024][256]
    const float* __restrict__ w_hh1,  // [1024][256]
    const float* __restrict__ b_ih1,
    const float* __restrict__ b_hh1,
    u32* __restrict__ h0p,            // [2][HB] packed hi|lo
    u32* __restrict__ h1p,            // [2][HB] packed hi|lo
    u32* __restrict__ flags)          // [NGRP][GBLK] stride 32 u32 (128 B)
{
    const int bid = blockIdx.x;
    const int tid = threadIdx.x;
    const int g     = bid >> 5;        // batch group 0..7
    const int rk    = bid & 31;        // rank in group
    const int layer = rk >> 4;         // 0 or 1
    const int ct    = rk & 15;         // col tile
    const int b0    = g * 16;          // 16 batches
    const int j0    = ct * 16;         // 16 h-cols

    const int wave = tid >> 6;
    const int l    = tid & 63;
    const int kq   = l >> 4;           // k-quarter within a k-tile
    const int ar   = l & 15;           // A row / B col (batch) within tile

    // bf16 planes of the [x;h] concat (k = 512; layer0 uses [0,320), rest 0)
    __shared__ __align__(16) unsigned short hsh[16 * 512];
    __shared__ __align__(16) unsigned short hsl[16 * 512];
    __shared__ float red[4][4][16][20];   // [wave][gate][batch(ar)][col], f4 st
    __shared__ float bbuf[4][16];         // bias sums [gate][col]

    // zero bf16 planes once (layer0's k >= 320 must stay 0 forever)
    {
        const short8 z8 = {0, 0, 0, 0, 0, 0, 0, 0};
        for (int i = tid; i < 16 * 512 / 8; i += 256) {
            ((short8*)hsh)[i] = z8;
            ((short8*)hsl)[i] = z8;
        }
    }
    if (tid < 64) {
        const int gg = tid >> 4, cc = tid & 15;
        const float* bi_ = layer ? b_ih1 : b_ih0;
        const float* bh_ = layer ? b_hh1 : b_hh0;
        bbuf[gg][cc] = bi_[gg * 256 + j0 + cc] + bh_[gg * 256 + j0 + cc];
    }

    // ---- A-fragments: weight slice -> bf16 hi/lo, resident in VGPRs ----
    // Frag layout (16x16x32): lane l holds A[row=l&15][k=(l>>4)*8 + j], j=0..7.
    short8 Ahi[4][4], Alo[4][4];  // [gate(Mtile)][wave-local ktile]
    {
        const short8 z8 = {0, 0, 0, 0, 0, 0, 0, 0};
        #pragma unroll
        for (int gg = 0; gg < 4; ++gg) {
            const int row = gg * 256 + j0 + ar;
            #pragma unroll
            for (int kt = 0; kt < 4; ++kt) {
                const int k = (wave * 4 + kt) * 32 + kq * 8;  // concat-k floats
                const float* src = nullptr;
                if (layer) {
                    src = (k < 256) ? (w_ih1 + (size_t)row * 256 + k)
                                    : (w_hh1 + (size_t)row * 256 + (k - 256));
                } else {
                    if (k < 64)       src = w_ih0 + (size_t)row * 64 + k;
                    else if (k < 320) src = w_hh0 + (size_t)row * 256 + (k - 64);
                }
                short8 hi8 = z8, lo8 = z8;
                if (src) {
                    const float4 a = ((const float4*)src)[0];
                    const float4 b = ((const float4*)src)[1];
                    const float wv[8] = {a.x, a.y, a.z, a.w, b.x, b.y, b.z, b.w};
                    #pragma unroll
                    for (int i = 0; i < 8; ++i) {
                        const unsigned short h = f2bf(wv[i]);
                        hi8[i] = (short)h;
                        lo8[i] = (short)f2bf(wv[i] - bf2f(h));
                    }
                }
                Ahi[gg][kt] = hi8;
                Alo[gg][kt] = lo8;
            }
        }
    }

    // elementwise ownership: thread (eb=batch, ecc=col); c stays in a register
    const int eb = tid >> 4, ecc = tid & 15;
    float creg = 0.f;

    u32* hown  = layer ? h1p : h0p;
    u32* gflag = flags + (size_t)g * GBLK * 32;
    const int hoff = layer ? 256 : 64;   // k-offset of the h_prev region

    // X prefetch (layer 0): one float4/thread covers 16 batches x 64 floats
    const int pb = tid >> 4, pf = tid & 15;
    float4 xpf = make_float4(0.f, 0.f, 0.f, 0.f);
    if (!layer)
        xpf = ((const float4*)(X + (size_t)(b0 + pb) * NFEAT))[pf];

    __syncthreads();  // LDS zero + bias visible

    for (int t = 0; t < SEQ; ++t) {
        // ---- WAIT: dependency-shaped poll, 4 overlapping samples/iter ----
        {
            u32 thr;
            int idx;
            if (tid < 16) {
                idx = layer * 16 + tid;
                thr = (u32)t;
                if (tid == ct) thr = 0;           // own flag trivially true
            } else {
                idx = (1 - layer) * 16 + (tid - 16);
                thr = layer ? (u32)(t + 1) : (u32)(t > 0 ? t - 1 : 0);
            }
            if (tid < 32 && thr > 0) {
                const u32* fp = &gflag[idx * 32];
                int guard = 0;
                for (;;) {
                    // 4 independent relaxed loads -> 4 samples per latency
                    const u32 s0 = ald32(fp);
                    const u32 s1 = ald32(fp);
                    const u32 s2 = ald32(fp);
                    const u32 s3 = ald32(fp);
                    if (s0 >= thr || s1 >= thr || s2 >= thr || s3 >= thr) break;
                    if ((guard += 4) >= (1 << 18)) break;
                }
            }
            __syncthreads();
        }

        const int par = t & 1, pp = par ^ 1;
        const int b = tid >> 4, f0 = tid & 15;   // staging: batch, chunk
        const int swz = (b & 7) << 3;

        if (t > 0) {  // h_prev (own layer), parity pp, packed words
            const u64* hp = (const u64*)(hown + (size_t)pp * HB
                                         + (size_t)(b0 + b) * HID + f0 * 16);
            u64 v[8];
            #pragma unroll
            for (int i = 0; i < 8; ++i) v[i] = ald64(hp + i);
            short8 h0v, l0v, h1v, l1v;
            #pragma unroll
            for (int i = 0; i < 4; ++i) {
                const u32 w0 = (u32)v[i], w1 = (u32)(v[i] >> 32);
                h0v[2*i]   = (short)(w0 >> 16); l0v[2*i]   = (short)(w0 & 0xffff);
                h0v[2*i+1] = (short)(w1 >> 16); l0v[2*i+1] = (short)(w1 & 0xffff);
                const u32 w2 = (u32)v[i+4], w3 = (u32)(v[i+4] >> 32);
                h1v[2*i]   = (short)(w2 >> 16); l1v[2*i]   = (short)(w2 & 0xffff);
                h1v[2*i+1] = (short)(w3 >> 16); l1v[2*i+1] = (short)(w3 & 0xffff);
            }
            const int us = b * 512 + hoff + f0 * 16;
            *(short8*)&hsh[us ^ swz]       = h0v;
            *(short8*)&hsh[(us + 8) ^ swz] = h1v;
            *(short8*)&hsl[us ^ swz]       = l0v;
            *(short8*)&hsl[(us + 8) ^ swz] = l1v;
        }
        if (layer) {  // x = h0[t], parity par, packed words
            const u64* xp = (const u64*)(h0p + (size_t)par * HB
                                         + (size_t)(b0 + b) * HID + f0 * 16);
            u64 v[8];
            #pragma unroll
            for (int i = 0; i < 8; ++i) v[i] = ald64(xp + i);
            short8 h0v, l0v, h1v, l1v;
            #pragma unroll
            for (int i = 0; i < 4; ++i) {
                const u32 w0 = (u32)v[i], w1 = (u32)(v[i] >> 32);
                h0v[2*i]   = (short)(w0 >> 16); l0v[2*i]   = (short)(w0 & 0xffff);
                h0v[2*i+1] = (short)(w1 >> 16); l0v[2*i+1] = (short)(w1 & 0xffff);
                const u32 w2 = (u32)v[i+4], w3 = (u32)(v[i+4] >> 32);
                h1v[2*i]   = (short)(w2 >> 16); l1v[2*i]   = (short)(w2 & 0xffff);
                h1v[2*i+1] = (short)(w3 >> 16); l1v[2*i+1] = (short)(w3 & 0xffff);
            }
            const int us = b * 512 + f0 * 16;
            *(short8*)&hsh[us ^ swz]       = h0v;
            *(short8*)&hsh[(us + 8) ^ swz] = h1v;
            *(short8*)&hsl[us ^ swz]       = l0v;
            *(short8*)&hsl[(us + 8) ^ swz] = l1v;
        } else {      // x from prefetched X (convert fp32 -> hi/lo)
            const float xv[4] = {xpf.x, xpf.y, xpf.z, xpf.w};
            us4 xh, xl;
            #pragma unroll
            for (int i = 0; i < 4; ++i) {
                const unsigned short hh = f2bf(xv[i]);
                xh[i] = hh;
                xl[i] = f2bf(xv[i] - bf2f(hh));
            }
            const int us = pb * 512 + pf * 4;
            const int sw = (pb & 7) << 3;
            *(us4*)&hsh[us ^ sw] = xh;
            *(us4*)&hsl[us ^ sw] = xl;
        }
        __syncthreads();  // S1: staged planes visible

        // next X prefetch (layer 0); has a full step to land
        if (!layer && t + 1 < SEQ)
            xpf = ((const float4*)(X + (size_t)(t + 1) * BATCH * NFEAT
                                     + (size_t)(b0 + pb) * NFEAT))[pf];

        {
            f32x4 acc[4];
            #pragma unroll
            for (int gg = 0; gg < 4; ++gg)
                acc[gg] = (f32x4){0.f, 0.f, 0.f, 0.f};

            #pragma unroll
            for (int kt = 0; kt < 4; ++kt) {
                const int KT = wave * 4 + kt;
                const int us = ar * 512 + KT * 32 + kq * 8;
                const int uswz = us ^ ((ar & 7) << 3);
                const short8 bh = *(const short8*)&hsh[uswz];
                const short8 bl = *(const short8*)&hsl[uswz];
                #pragma unroll
                for (int gg = 0; gg < 4; ++gg)
                    acc[gg] = __builtin_amdgcn_mfma_f32_16x16x32_bf16(
                        Ahi[gg][kt], bh, acc[gg], 0, 0, 0);
                #pragma unroll
                for (int gg = 0; gg < 4; ++gg)
                    acc[gg] = __builtin_amdgcn_mfma_f32_16x16x32_bf16(
                        Alo[gg][kt], bh, acc[gg], 0, 0, 0);
                #pragma unroll
                for (int gg = 0; gg < 4; ++gg)
                    acc[gg] = __builtin_amdgcn_mfma_f32_16x16x32_bf16(
                        Ahi[gg][kt], bl, acc[gg], 0, 0, 0);
            }
            // partial C -> LDS; C layout: col(batch)=ar, row(colidx)=kq*4+i
            #pragma unroll
            for (int gg = 0; gg < 4; ++gg)
                *(f32x4*)&red[wave][gg][ar][kq * 4] = acc[gg];
        }
        __syncthreads();  // S2: partials visible

        {
            float p[4];
            #pragma unroll
            for (int gg = 0; gg < 4; ++gg)
                p[gg] = bbuf[gg][ecc] + red[0][gg][eb][ecc] + red[1][gg][eb][ecc]
                                      + red[2][gg][eb][ecc] + red[3][gg][eb][ecc];
            const float ig  = 1.0f / (1.0f + __expf(-p[0]));
            const float fg  = 1.0f / (1.0f + __expf(-p[1]));
            const float gg_ = tanhf(p[2]);
            const float og  = 1.0f / (1.0f + __expf(-p[3]));
            creg = fg * creg + ig * gg_;
            const float hv = og * tanhf(creg);
            // pack hi|lo and publish via agent-scope store (IF coherent)
            const unsigned short hi = f2bf(hv);
            const unsigned short lo = f2bf(hv - bf2f(hi));
            ast32(&hown[(size_t)par * HB + (size_t)(b0 + eb) * HID + j0 + ecc],
                  ((u32)hi << 16) | (u32)lo);
        }

        // ---- completion post: drain h stores, then flag = t+1 ----
        __syncthreads();  // drains vmcnt: all h stores acked at coherence point
        if (tid == 0)
            ast32(&gflag[rk * 32], (u32)(t + 1));
        // next iteration's WAIT syncthreads separates LDS reuse (red/hs*)
    }
}

// out[b] = dot(h1_last[b,:], fc_w) + fc_b ; h1 arrives as packed hi|lo words
__global__ __launch_bounds__(64) void fc_kernel(
    const u32* __restrict__ h1last_p,
    const float* __restrict__ fc_w,
    const float* __restrict__ fc_b,
    float* __restrict__ out)
{
    const int b    = blockIdx.x;
    const int lane = threadIdx.x;
    float sum = 0.0f;
    #pragma unroll
    for (int k = lane; k < HID; k += 64) {
        const u32 w = h1last_p[(size_t)b * HID + k];
        const float h = bf2f((unsigned short)(w >> 16))
                      + bf2f((unsigned short)(w & 0xffff));
        sum += h * fc_w[k];
    }
    #pragma unroll
    for (int off = 32; off > 0; off >>= 1)
        sum += __shfl_down(sum, off);
    if (lane == 0) out[b] = sum + fc_b[0];
}

extern "C" void kernel_launch(void* const* d_in, const int* in_sizes, int n_in,
                              void* d_out, int out_size, void* d_ws, size_t ws_size,
                              hipStream_t stream)
{
    const float* X     = (const float*)d_in[0];
    const float* w_ih0 = (const float*)d_in[1];
    const float* w_hh0 = (const float*)d_in[2];
    const float* b_ih0 = (const float*)d_in[3];
    const float* b_hh0 = (const float*)d_in[4];
    const float* w_ih1 = (const float*)d_in[5];
    const float* w_hh1 = (const float*)d_in[6];
    const float* b_ih1 = (const float*)d_in[7];
    const float* b_hh1 = (const float*)d_in[8];
    const float* fc_w  = (const float*)d_in[9];
    const float* fc_b  = (const float*)d_in[10];

    u32* h0p   = (u32*)d_ws;             // [2][HB] packed
    u32* h1p   = h0p + 2 * HB;           // [2][HB] packed
    u32* flags = h1p + 2 * HB;           // NGRP*GBLK slots, stride 32 u32

    // zero h buffers + flags every call (graph replays the memset, so stale
    // state can never leak across replays)
    const size_t zbytes = (size_t)(4 * HB + NGRP * GBLK * 32) * sizeof(u32);
    (void)hipMemsetAsync(d_ws, 0, zbytes, stream);

    lstm_persist<<<NGRP * GBLK, 256, 0, stream>>>(X,
        w_ih0, w_hh0, b_ih0, b_hh0,
        w_ih1, w_hh1, b_ih1, b_hh1,
        h0p, h1p, flags);

    // h1 for t=511 lives in parity buffer (511 & 1) = 1
    fc_kernel<<<BATCH, 64, 0, stream>>>(h1p + HB, fc_w, fc_b, (float*)d_out);
}

// Round 17
// 2107.200 us; speedup vs baseline: 2.0011x; 1.2141x over previous
//
#include <hip/hip_runtime.h>

#define SEQ   512
#define BATCH 128
#define NFEAT 64
#define HID   256
#define HB    (BATCH * HID)   // 32768
#define NGRP  8               // batch groups (16 batches each)
#define GBLK  32              // blocks per group: 2 layers x 16 col-tiles

// ---------------------------------------------------------------------------
// Persistent 2-layer LSTM, 256 blocks x 256 threads (1 block/CU).
// FINAL FORM: this is the round-10 kernel byte-for-byte -- the best verified
// configuration (2096us, absmax 0.0). Rounds 11-16 tested: XCD-local sc0
// exchange (wrong data -- blacklisted), single-trip tagged words (neutral),
// batch interleaving (regressed), per-wave full-K no-reduce (regressed,
// spill), pipelined polling (regressed + codegen risk). Conclusion: the step
// time = fabric store->observe latency (~2.5us, protocol-invariant) + lean
// compute (~1.6us); this kernel sits at that floor.
// Sync: dependency-shaped flags. Flag[rk]=v <=> block rk completed step v-1.
// At step t: L0 waits own flag0[*]>=t, cross flag1[*]>=t-1; L1 waits own
// flag1[*]>=t, cross flag0[*]>=t+1. One poll phase + one flag post per step.
// h crosses blocks as packed u32 [bf16_hi|bf16_lo]. Memory primitives: ONLY
// agent-scope relaxed atomics (r6/r9/r10-verified).
// Matmul: r6-verified MFMA bf16 hi/lo split, A-frags resident (AGPR/VGPR),
// XOR-swizzled LDS B-planes, partial C as float4 into red[4][4][16][20].
// c state stays in its owning thread's register.
// ---------------------------------------------------------------------------

typedef unsigned u32;
typedef unsigned long long u64;
typedef __attribute__((ext_vector_type(8))) short  short8;
typedef __attribute__((ext_vector_type(4))) float  f32x4;
typedef __attribute__((ext_vector_type(4))) unsigned short us4;

__device__ __forceinline__ unsigned short f2bf(float f) {  // RNE
    union { float f; unsigned u; } c; c.f = f;
    unsigned r = c.u + 0x7FFF + ((c.u >> 16) & 1);
    return (unsigned short)(r >> 16);
}
__device__ __forceinline__ float bf2f(unsigned short h) {
    union { float f; unsigned u; } c; c.u = ((unsigned)h) << 16;
    return c.f;
}

// agent-scope (IF coherence point) relaxed atomics -- the ONLY cross-block
// memory primitives in this kernel (r6/r9/r10-verified codegen).
__device__ __forceinline__ u64 ald64(const u64* p) {
    return __hip_atomic_load(p, __ATOMIC_RELAXED, __HIP_MEMORY_SCOPE_AGENT);
}
__device__ __forceinline__ u32 ald32(const u32* p) {
    return __hip_atomic_load(p, __ATOMIC_RELAXED, __HIP_MEMORY_SCOPE_AGENT);
}
__device__ __forceinline__ void ast32(u32* p, u32 v) {
    __hip_atomic_store(p, v, __ATOMIC_RELAXED, __HIP_MEMORY_SCOPE_AGENT);
}

__global__ __launch_bounds__(256, 1) void lstm_persist(
    const float* __restrict__ X,      // [512][128][64]
    const float* __restrict__ w_ih0,  // [1024][64]
    const float* __restrict__ w_hh0,  // [1024][256]
    const float* __restrict__ b_ih0,
    const float* __restrict__ b_hh0,
    const float* __restrict__ w_ih1,  // [1024][256]
    const float* __restrict__ w_hh1,  // [1024][256]
    const float* __restrict__ b_ih1,
    const float* __restrict__ b_hh1,
    u32* __restrict__ h0p,            // [2][HB] packed hi|lo
    u32* __restrict__ h1p,            // [2][HB] packed hi|lo
    u32* __restrict__ flags)          // [NGRP][GBLK] stride 32 u32 (128 B)
{
    const int bid = blockIdx.x;
    const int tid = threadIdx.x;
    const int g     = bid >> 5;        // batch group 0..7
    const int rk    = bid & 31;        // rank in group
    const int layer = rk >> 4;         // 0 or 1
    const int ct    = rk & 15;         // col tile
    const int b0    = g * 16;          // 16 batches
    const int j0    = ct * 16;         // 16 h-cols

    const int wave = tid >> 6;
    const int l    = tid & 63;
    const int kq   = l >> 4;           // k-quarter within a k-tile
    const int ar   = l & 15;           // A row / B col (batch) within tile

    // bf16 planes of the [x;h] concat (k = 512; layer0 uses [0,320), rest 0)
    __shared__ __align__(16) unsigned short hsh[16 * 512];
    __shared__ __align__(16) unsigned short hsl[16 * 512];
    __shared__ float red[4][4][16][20];   // [wave][gate][batch(ar)][col], f4 st
    __shared__ float bbuf[4][16];         // bias sums [gate][col]

    // zero bf16 planes once (layer0's k >= 320 must stay 0 forever)
    {
        const short8 z8 = {0, 0, 0, 0, 0, 0, 0, 0};
        for (int i = tid; i < 16 * 512 / 8; i += 256) {
            ((short8*)hsh)[i] = z8;
            ((short8*)hsl)[i] = z8;
        }
    }
    if (tid < 64) {
        const int gg = tid >> 4, cc = tid & 15;
        const float* bi_ = layer ? b_ih1 : b_ih0;
        const float* bh_ = layer ? b_hh1 : b_hh0;
        bbuf[gg][cc] = bi_[gg * 256 + j0 + cc] + bh_[gg * 256 + j0 + cc];
    }

    // ---- A-fragments: weight slice -> bf16 hi/lo, resident in VGPRs ----
    // Frag layout (16x16x32): lane l holds A[row=l&15][k=(l>>4)*8 + j], j=0..7.
    short8 Ahi[4][4], Alo[4][4];  // [gate(Mtile)][wave-local ktile]
    {
        const short8 z8 = {0, 0, 0, 0, 0, 0, 0, 0};
        #pragma unroll
        for (int gg = 0; gg < 4; ++gg) {
            const int row = gg * 256 + j0 + ar;
            #pragma unroll
            for (int kt = 0; kt < 4; ++kt) {
                const int k = (wave * 4 + kt) * 32 + kq * 8;  // concat-k floats
                const float* src = nullptr;
                if (layer) {
                    src = (k < 256) ? (w_ih1 + (size_t)row * 256 + k)
                                    : (w_hh1 + (size_t)row * 256 + (k - 256));
                } else {
                    if (k < 64)       src = w_ih0 + (size_t)row * 64 + k;
                    else if (k < 320) src = w_hh0 + (size_t)row * 256 + (k - 64);
                }
                short8 hi8 = z8, lo8 = z8;
                if (src) {
                    const float4 a = ((const float4*)src)[0];
                    const float4 b = ((const float4*)src)[1];
                    const float wv[8] = {a.x, a.y, a.z, a.w, b.x, b.y, b.z, b.w};
                    #pragma unroll
                    for (int i = 0; i < 8; ++i) {
                        const unsigned short h = f2bf(wv[i]);
                        hi8[i] = (short)h;
                        lo8[i] = (short)f2bf(wv[i] - bf2f(h));
                    }
                }
                Ahi[gg][kt] = hi8;
                Alo[gg][kt] = lo8;
            }
        }
    }

    // elementwise ownership: thread (eb=batch, ecc=col); c stays in a register
    const int eb = tid >> 4, ecc = tid & 15;
    float creg = 0.f;

    u32* hown  = layer ? h1p : h0p;
    u32* gflag = flags + (size_t)g * GBLK * 32;
    const int hoff = layer ? 256 : 64;   // k-offset of the h_prev region

    // X prefetch (layer 0): one float4/thread covers 16 batches x 64 floats
    const int pb = tid >> 4, pf = tid & 15;
    float4 xpf = make_float4(0.f, 0.f, 0.f, 0.f);
    if (!layer)
        xpf = ((const float4*)(X + (size_t)(b0 + pb) * NFEAT))[pf];

    __syncthreads();  // LDS zero + bias visible

    for (int t = 0; t < SEQ; ++t) {
        // ---- WAIT: dependency-shaped poll (32 lanes, hot spin) ----
        {
            // lane < 16: own-layer flag[lane] >= t          (skip lane == ct)
            // lane in [16,32): other-layer flag[lane-16] >= (L1 ? t+1 : t-1)
            u32 thr;
            int idx;
            if (tid < 16) {
                idx = layer * 16 + tid;
                thr = (u32)t;
                if (tid == ct) thr = 0;           // own flag trivially true
            } else {
                idx = (1 - layer) * 16 + (tid - 16);
                thr = layer ? (u32)(t + 1) : (u32)(t > 0 ? t - 1 : 0);
            }
            if (tid < 32 && thr > 0) {
                int guard = 0;
                while (ald32(&gflag[idx * 32]) < thr && ++guard < (1 << 18)) {}
            }
            __syncthreads();
        }

        const int par = t & 1, pp = par ^ 1;
        const int b = tid >> 4, f0 = tid & 15;   // staging: batch, chunk
        const int swz = (b & 7) << 3;

        if (t > 0) {  // h_prev (own layer), parity pp, packed words
            const u64* hp = (const u64*)(hown + (size_t)pp * HB
                                         + (size_t)(b0 + b) * HID + f0 * 16);
            u64 v[8];
            #pragma unroll
            for (int i = 0; i < 8; ++i) v[i] = ald64(hp + i);
            short8 h0v, l0v, h1v, l1v;
            #pragma unroll
            for (int i = 0; i < 4; ++i) {
                const u32 w0 = (u32)v[i], w1 = (u32)(v[i] >> 32);
                h0v[2*i]   = (short)(w0 >> 16); l0v[2*i]   = (short)(w0 & 0xffff);
                h0v[2*i+1] = (short)(w1 >> 16); l0v[2*i+1] = (short)(w1 & 0xffff);
                const u32 w2 = (u32)v[i+4], w3 = (u32)(v[i+4] >> 32);
                h1v[2*i]   = (short)(w2 >> 16); l1v[2*i]   = (short)(w2 & 0xffff);
                h1v[2*i+1] = (short)(w3 >> 16); l1v[2*i+1] = (short)(w3 & 0xffff);
            }
            const int us = b * 512 + hoff + f0 * 16;
            *(short8*)&hsh[us ^ swz]       = h0v;
            *(short8*)&hsh[(us + 8) ^ swz] = h1v;
            *(short8*)&hsl[us ^ swz]       = l0v;
            *(short8*)&hsl[(us + 8) ^ swz] = l1v;
        }
        if (layer) {  // x = h0[t], parity par, packed words
            const u64* xp = (const u64*)(h0p + (size_t)par * HB
                                         + (size_t)(b0 + b) * HID + f0 * 16);
            u64 v[8];
            #pragma unroll
            for (int i = 0; i < 8; ++i) v[i] = ald64(xp + i);
            short8 h0v, l0v, h1v, l1v;
            #pragma unroll
            for (int i = 0; i < 4; ++i) {
                const u32 w0 = (u32)v[i], w1 = (u32)(v[i] >> 32);
                h0v[2*i]   = (short)(w0 >> 16); l0v[2*i]   = (short)(w0 & 0xffff);
                h0v[2*i+1] = (short)(w1 >> 16); l0v[2*i+1] = (short)(w1 & 0xffff);
                const u32 w2 = (u32)v[i+4], w3 = (u32)(v[i+4] >> 32);
                h1v[2*i]   = (short)(w2 >> 16); l1v[2*i]   = (short)(w2 & 0xffff);
                h1v[2*i+1] = (short)(w3 >> 16); l1v[2*i+1] = (short)(w3 & 0xffff);
            }
            const int us = b * 512 + f0 * 16;
            *(short8*)&hsh[us ^ swz]       = h0v;
            *(short8*)&hsh[(us + 8) ^ swz] = h1v;
            *(short8*)&hsl[us ^ swz]       = l0v;
            *(short8*)&hsl[(us + 8) ^ swz] = l1v;
        } else {      // x from prefetched X (convert fp32 -> hi/lo)
            const float xv[4] = {xpf.x, xpf.y, xpf.z, xpf.w};
            us4 xh, xl;
            #pragma unroll
            for (int i = 0; i < 4; ++i) {
                const unsigned short hh = f2bf(xv[i]);
                xh[i] = hh;
                xl[i] = f2bf(xv[i] - bf2f(hh));
            }
            const int us = pb * 512 + pf * 4;
            const int sw = (pb & 7) << 3;
            *(us4*)&hsh[us ^ sw] = xh;
            *(us4*)&hsl[us ^ sw] = xl;
        }
        __syncthreads();  // S1: staged planes visible

        // next X prefetch (layer 0); has a full step to land
        if (!layer && t + 1 < SEQ)
            xpf = ((const float4*)(X + (size_t)(t + 1) * BATCH * NFEAT
                                     + (size_t)(b0 + pb) * NFEAT))[pf];

        {
            f32x4 acc[4];
            #pragma unroll
            for (int gg = 0; gg < 4; ++gg)
                acc[gg] = (f32x4){0.f, 0.f, 0.f, 0.f};

            #pragma unroll
            for (int kt = 0; kt < 4; ++kt) {
                const int KT = wave * 4 + kt;
                const int us = ar * 512 + KT * 32 + kq * 8;
                const int uswz = us ^ ((ar & 7) << 3);
                const short8 bh = *(const short8*)&hsh[uswz];
                const short8 bl = *(const short8*)&hsl[uswz];
                #pragma unroll
                for (int gg = 0; gg < 4; ++gg)
                    acc[gg] = __builtin_amdgcn_mfma_f32_16x16x32_bf16(
                        Ahi[gg][kt], bh, acc[gg], 0, 0, 0);
                #pragma unroll
                for (int gg = 0; gg < 4; ++gg)
                    acc[gg] = __builtin_amdgcn_mfma_f32_16x16x32_bf16(
                        Alo[gg][kt], bh, acc[gg], 0, 0, 0);
                #pragma unroll
                for (int gg = 0; gg < 4; ++gg)
                    acc[gg] = __builtin_amdgcn_mfma_f32_16x16x32_bf16(
                        Ahi[gg][kt], bl, acc[gg], 0, 0, 0);
            }
            // partial C -> LDS; C layout: col(batch)=ar, row(colidx)=kq*4+i
            #pragma unroll
            for (int gg = 0; gg < 4; ++gg)
                *(f32x4*)&red[wave][gg][ar][kq * 4] = acc[gg];
        }
        __syncthreads();  // S2: partials visible

        {
            float p[4];
            #pragma unroll
            for (int gg = 0; gg < 4; ++gg)
                p[gg] = bbuf[gg][ecc] + red[0][gg][eb][ecc] + red[1][gg][eb][ecc]
                                      + red[2][gg][eb][ecc] + red[3][gg][eb][ecc];
            const float ig  = 1.0f / (1.0f + __expf(-p[0]));
            const float fg  = 1.0f / (1.0f + __expf(-p[1]));
            const float gg_ = tanhf(p[2]);
            const float og  = 1.0f / (1.0f + __expf(-p[3]));
            creg = fg * creg + ig * gg_;
            const float hv = og * tanhf(creg);
            // pack hi|lo and publish via agent-scope store (IF coherent)
            const unsigned short hi = f2bf(hv);
            const unsigned short lo = f2bf(hv - bf2f(hi));
            ast32(&hown[(size_t)par * HB + (size_t)(b0 + eb) * HID + j0 + ecc],
                  ((u32)hi << 16) | (u32)lo);
        }

        // ---- completion post: drain h stores, then flag = t+1 ----
        __syncthreads();  // drains vmcnt: all h stores acked at coherence point
        if (tid == 0)
            ast32(&gflag[rk * 32], (u32)(t + 1));
        // next iteration's WAIT syncthreads separates LDS reuse (red/hs*)
    }
}

// out[b] = dot(h1_last[b,:], fc_w) + fc_b ; h1 arrives as packed hi|lo words
__global__ __launch_bounds__(64) void fc_kernel(
    const u32* __restrict__ h1last_p,
    const float* __restrict__ fc_w,
    const float* __restrict__ fc_b,
    float* __restrict__ out)
{
    const int b    = blockIdx.x;
    const int lane = threadIdx.x;
    float sum = 0.0f;
    #pragma unroll
    for (int k = lane; k < HID; k += 64) {
        const u32 w = h1last_p[(size_t)b * HID + k];
        const float h = bf2f((unsigned short)(w >> 16))
                      + bf2f((unsigned short)(w & 0xffff));
        sum += h * fc_w[k];
    }
    #pragma unroll
    for (int off = 32; off > 0; off >>= 1)
        sum += __shfl_down(sum, off);
    if (lane == 0) out[b] = sum + fc_b[0];
}

extern "C" void kernel_launch(void* const* d_in, const int* in_sizes, int n_in,
                              void* d_out, int out_size, void* d_ws, size_t ws_size,
                              hipStream_t stream)
{
    const float* X     = (const float*)d_in[0];
    const float* w_ih0 = (const float*)d_in[1];
    const float* w_hh0 = (const float*)d_in[2];
    const float* b_ih0 = (const float*)d_in[3];
    const float* b_hh0 = (const float*)d_in[4];
    const float* w_ih1 = (const float*)d_in[5];
    const float* w_hh1 = (const float*)d_in[6];
    const float* b_ih1 = (const float*)d_in[7];
    const float* b_hh1 = (const float*)d_in[8];
    const float* fc_w  = (const float*)d_in[9];
    const float* fc_b  = (const float*)d_in[10];

    u32* h0p   = (u32*)d_ws;             // [2][HB] packed
    u32* h1p   = h0p + 2 * HB;           // [2][HB] packed
    u32* flags = h1p + 2 * HB;           // NGRP*GBLK slots, stride 32 u32

    // zero h buffers + flags every call (graph replays the memset, so stale
    // state can never leak across replays)
    const size_t zbytes = (size_t)(4 * HB + NGRP * GBLK * 32) * sizeof(u32);
    (void)hipMemsetAsync(d_ws, 0, zbytes, stream);

    lstm_persist<<<NGRP * GBLK, 256, 0, stream>>>(X,
        w_ih0, w_hh0, b_ih0, b_hh0,
        w_ih1, w_hh1, b_ih1, b_hh1,
        h0p, h1p, flags);

    // h1 for t=511 lives in parity buffer (511 & 1) = 1
    fc_kernel<<<BATCH, 64, 0, stream>>>(h1p + HB, fc_w, fc_b, (float*)d_out);
}